// Round 1
// baseline (854.181 us; speedup 1.0000x reference)
//
#include <hip/hip_runtime.h>
#include <hip/hip_bf16.h>
#include <cstdint>

// Problem constants
#define B_   2
#define NQ_  10000
#define C_   256
#define NH_  8
#define DH_  32
#define L_   4
#define P_   4
#define DFF_ 1024
#define S_   19560

__constant__ int dummy_unused; // keep toolchain happy

// ---------------------------------------------------------------- add kernel
__global__ __launch_bounds__(256) void add_kernel(const float* __restrict__ a,
                                                  const float* __restrict__ b,
                                                  float* __restrict__ o, int n4) {
  int i = blockIdx.x * 256 + threadIdx.x;
  if (i >= n4) return;
  float4 x = reinterpret_cast<const float4*>(a)[i];
  float4 y = reinterpret_cast<const float4*>(b)[i];
  float4 z;
  z.x = x.x + y.x; z.y = x.y + y.y; z.z = x.z + y.z; z.w = x.w + y.w;
  reinterpret_cast<float4*>(o)[i] = z;
}

// ---------------------------------------------------------------- fp32 GEMM
// C[M,N] = A[M,K] @ B[K,N] + bias[N], optional ReLU. Row-major everywhere.
// 64x64 tile, BK=16, 256 threads, 4x4 per thread.
template <bool RELU>
__global__ __launch_bounds__(256) void gemm_f32(const float* __restrict__ A,
                                                const float* __restrict__ Bm,
                                                const float* __restrict__ bias,
                                                float* __restrict__ Cm,
                                                int M, int N, int K) {
  __shared__ float As[16][65];
  __shared__ float Bs[16][68];
  const int tid = threadIdx.x;
  const int tx = tid & 15;        // N direction (x4)
  const int ty = tid >> 4;        // M direction (x4)
  const long bm = (long)blockIdx.x * 64;
  const long bn = (long)blockIdx.y * 64;
  float acc[4][4] = {};

  const int arow = tid >> 2;            // 0..63
  const int acol = (tid & 3) << 2;      // 0,4,8,12
  const int brow = tid >> 4;            // 0..15
  const int bcol = (tid & 15) << 2;     // 0..60
  const bool aval = (bm + arow) < M;
  const float* Ap = A + (bm + arow) * (long)K + acol;

  for (int k0 = 0; k0 < K; k0 += 16) {
    float4 av = make_float4(0.f, 0.f, 0.f, 0.f);
    if (aval) av = *reinterpret_cast<const float4*>(Ap + k0);
    float4 bv = *reinterpret_cast<const float4*>(Bm + (long)(k0 + brow) * N + bn + bcol);
    As[acol + 0][arow] = av.x;
    As[acol + 1][arow] = av.y;
    As[acol + 2][arow] = av.z;
    As[acol + 3][arow] = av.w;
    *reinterpret_cast<float4*>(&Bs[brow][bcol]) = bv;
    __syncthreads();
#pragma unroll
    for (int kk = 0; kk < 16; ++kk) {
      float a0 = As[kk][ty * 4 + 0];
      float a1 = As[kk][ty * 4 + 1];
      float a2 = As[kk][ty * 4 + 2];
      float a3 = As[kk][ty * 4 + 3];
      float b0 = Bs[kk][tx * 4 + 0];
      float b1 = Bs[kk][tx * 4 + 1];
      float b2 = Bs[kk][tx * 4 + 2];
      float b3 = Bs[kk][tx * 4 + 3];
      acc[0][0] += a0 * b0; acc[0][1] += a0 * b1; acc[0][2] += a0 * b2; acc[0][3] += a0 * b3;
      acc[1][0] += a1 * b0; acc[1][1] += a1 * b1; acc[1][2] += a1 * b2; acc[1][3] += a1 * b3;
      acc[2][0] += a2 * b0; acc[2][1] += a2 * b1; acc[2][2] += a2 * b2; acc[2][3] += a2 * b3;
      acc[3][0] += a3 * b0; acc[3][1] += a3 * b1; acc[3][2] += a3 * b2; acc[3][3] += a3 * b3;
    }
    __syncthreads();
  }
#pragma unroll
  for (int i = 0; i < 4; ++i) {
    long r = bm + ty * 4 + i;
    if (r >= M) continue;
    float4 o;
    o.x = acc[i][0] + bias[bn + tx * 4 + 0];
    o.y = acc[i][1] + bias[bn + tx * 4 + 1];
    o.z = acc[i][2] + bias[bn + tx * 4 + 2];
    o.w = acc[i][3] + bias[bn + tx * 4 + 3];
    if (RELU) {
      o.x = fmaxf(o.x, 0.f); o.y = fmaxf(o.y, 0.f);
      o.z = fmaxf(o.z, 0.f); o.w = fmaxf(o.w, 0.f);
    }
    *reinterpret_cast<float4*>(Cm + r * (long)N + bn + tx * 4) = o;
  }
}

// ---------------------------------------------------------------- softmax(16)
// attn logits [n, 16] -> softmax over last dim, in place.
__global__ __launch_bounds__(256) void softmax16_kernel(float* __restrict__ attn, int n) {
  int i = blockIdx.x * 256 + threadIdx.x;
  if (i >= n) return;
  float* p = attn + (long)i * 16;
  float v[16];
#pragma unroll
  for (int j = 0; j < 4; ++j) {
    float4 t = reinterpret_cast<const float4*>(p)[j];
    v[j * 4 + 0] = t.x; v[j * 4 + 1] = t.y; v[j * 4 + 2] = t.z; v[j * 4 + 3] = t.w;
  }
  float m = v[0];
#pragma unroll
  for (int j = 1; j < 16; ++j) m = fmaxf(m, v[j]);
  float s = 0.f;
#pragma unroll
  for (int j = 0; j < 16; ++j) { v[j] = expf(v[j] - m); s += v[j]; }
  float inv = 1.f / s;
#pragma unroll
  for (int j = 0; j < 4; ++j) {
    float4 t;
    t.x = v[j * 4 + 0] * inv; t.y = v[j * 4 + 1] * inv;
    t.z = v[j * 4 + 2] * inv; t.w = v[j * 4 + 3] * inv;
    reinterpret_cast<float4*>(p)[j] = t;
  }
}

// ---------------------------------------------------------------- ms_deform
// value [B,S,NH,DH], off [B*NQ,256] (h,l,p,2), attn [B*NQ,128] (h,l*p),
// q_ref [B*NQ,2], vr [B,L,2] -> out [B*NQ, 256] (h,dh)
__global__ __launch_bounds__(256) void msdeform_kernel(
    const float* __restrict__ value, const float* __restrict__ off,
    const float* __restrict__ attn, const float* __restrict__ q_ref,
    const float* __restrict__ vr, float* __restrict__ out) {
  const int LVL_H[4] = {92, 46, 23, 12};
  const int LVL_W[4] = {160, 80, 40, 20};
  const int LVL_S[4] = {0, 14720, 18400, 19320};

  int t = blockIdx.x * 256 + threadIdx.x;
  int d = t & 31;
  int idx = t >> 5;                    // b*NQ*NH + q*NH + h
  if (idx >= B_ * NQ_ * NH_) return;
  int h = idx & 7;
  int bq = idx >> 3;                   // b*NQ + q
  int b = bq / NQ_;

  float rx = q_ref[(long)bq * 2 + 0];
  float ry = q_ref[(long)bq * 2 + 1];
  const float* offp = off + (long)bq * 256 + h * 32;   // h*L*P*2
  const float* attp = attn + (long)bq * 128 + h * 16;  // h*L*P
  float acc = 0.f;

#pragma unroll
  for (int l = 0; l < 4; ++l) {
    const int H = LVL_H[l], W = LVL_W[l];
    float vrx = vr[(b * 4 + l) * 2 + 0];
    float vry = vr[(b * 4 + l) * 2 + 1];
    float refx = rx * vrx, refy = ry * vry;
    const float* vbase = value + ((long)(b * S_ + LVL_S[l]) * NH_ + h) * DH_ + d;
#pragma unroll
    for (int p = 0; p < 4; ++p) {
      float ox = offp[(l * 4 + p) * 2 + 0];
      float oy = offp[(l * 4 + p) * 2 + 1];
      float aw = attp[l * 4 + p];
      // loc = ref + off/normalizer; x = loc_x*W - 0.5
      float x = (refx + ox * (1.f / W)) * W - 0.5f;
      float y = (refy + oy * (1.f / H)) * H - 0.5f;
      float x0f = floorf(x), y0f = floorf(y);
      float lx = x - x0f, ly = y - y0f;
      int x0 = (int)x0f, y0 = (int)y0f;
      int x1 = x0 + 1, y1 = y0 + 1;
      float w00 = (1.f - lx) * (1.f - ly);
      float w10 = lx * (1.f - ly);
      float w01 = (1.f - lx) * ly;
      float w11 = lx * ly;
      if (x0 >= 0 && x0 < W && y0 >= 0 && y0 < H)
        acc += aw * w00 * vbase[(long)(y0 * W + x0) * 256];
      if (x1 >= 0 && x1 < W && y0 >= 0 && y0 < H)
        acc += aw * w10 * vbase[(long)(y0 * W + x1) * 256];
      if (x0 >= 0 && x0 < W && y1 >= 0 && y1 < H)
        acc += aw * w01 * vbase[(long)(y1 * W + x0) * 256];
      if (x1 >= 0 && x1 < W && y1 >= 0 && y1 < H)
        acc += aw * w11 * vbase[(long)(y1 * W + x1) * 256];
    }
  }
  out[(long)bq * 256 + h * 32 + d] = acc;
}

// ---------------------------------------------------------------- residual+LN
// out = LN(res + xin) * gamma + beta, rows of 256. One wave per row.
__global__ __launch_bounds__(256) void add_ln_kernel(
    const float* __restrict__ res, const float* __restrict__ xin,
    const float* __restrict__ gamma, const float* __restrict__ beta,
    float* __restrict__ out, int nrows) {
  int row = blockIdx.x * 4 + (threadIdx.x >> 6);
  int lane = threadIdx.x & 63;
  if (row >= nrows) return;
  const float4 r4 = *reinterpret_cast<const float4*>(res + (long)row * 256 + lane * 4);
  const float4 x4 = *reinterpret_cast<const float4*>(xin + (long)row * 256 + lane * 4);
  float tv[4] = {r4.x + x4.x, r4.y + x4.y, r4.z + x4.z, r4.w + x4.w};
  float s = tv[0] + tv[1] + tv[2] + tv[3];
#pragma unroll
  for (int o = 32; o > 0; o >>= 1) s += __shfl_xor(s, o, 64);
  float mean = s * (1.f / 256.f);
  float vs = 0.f;
#pragma unroll
  for (int j = 0; j < 4; ++j) {
    float dd = tv[j] - mean;
    vs += dd * dd;
  }
#pragma unroll
  for (int o = 32; o > 0; o >>= 1) vs += __shfl_xor(vs, o, 64);
  float inv = rsqrtf(vs * (1.f / 256.f) + 1e-5f);
  const float4 g = *reinterpret_cast<const float4*>(gamma + lane * 4);
  const float4 be = *reinterpret_cast<const float4*>(beta + lane * 4);
  float4 o4;
  o4.x = (tv[0] - mean) * inv * g.x + be.x;
  o4.y = (tv[1] - mean) * inv * g.y + be.y;
  o4.z = (tv[2] - mean) * inv * g.z + be.z;
  o4.w = (tv[3] - mean) * inv * g.w + be.w;
  *reinterpret_cast<float4*>(out + (long)row * 256 + lane * 4) = o4;
}

// ---------------------------------------------------------------- launch
extern "C" void kernel_launch(void* const* d_in, const int* in_sizes, int n_in,
                              void* d_out, int out_size, void* d_ws, size_t ws_size,
                              hipStream_t stream) {
  const float* src    = (const float*)d_in[0];
  const float* q_feat = (const float*)d_in[1];
  const float* q_pos  = (const float*)d_in[2];
  const float* q_ref  = (const float*)d_in[3];
  const float* vr     = (const float*)d_in[4];
  const float* Wv     = (const float*)d_in[5];
  const float* bv     = (const float*)d_in[6];
  const float* Woff   = (const float*)d_in[7];
  const float* boff   = (const float*)d_in[8];
  const float* Wa     = (const float*)d_in[9];
  const float* ba     = (const float*)d_in[10];
  const float* Wo     = (const float*)d_in[11];
  const float* bo     = (const float*)d_in[12];
  const float* g1     = (const float*)d_in[13];
  const float* be1    = (const float*)d_in[14];
  const float* W1     = (const float*)d_in[15];
  const float* bf1    = (const float*)d_in[16];
  const float* W2     = (const float*)d_in[17];
  const float* bf2    = (const float*)d_in[18];
  const float* g2     = (const float*)d_in[19];
  const float* be2    = (const float*)d_in[20];

  float* ws = (float*)d_ws;
  // layout (floats): q[5.12M] value[10.01M] off[5.12M] attn[2.56M] ms[5.12M] x[5.12M]
  float* ws_q   = ws + 0L;
  float* ws_val = ws + 5120000L;
  float* ws_off = ws + 15134720L;
  float* ws_att = ws + 20254720L;
  float* ws_ms  = ws + 22814720L;
  float* ws_x   = ws + 27934720L;
  float* ws_a   = ws + 0L;         // reuse q region (q dead after off/attn GEMMs)
  float* ws_h1  = ws + 0L;         // reuse q..attn region (all dead after sampling)
  float* ws_f2  = ws + 22814720L;  // reuse ms region (dead after proj GEMM)
  float* outp = (float*)d_out;

  const int Mq = B_ * NQ_;   // 20000
  const int Mv = B_ * S_;    // 39120

  // q = q_feat + q_pos
  add_kernel<<<(Mq * C_ / 4 + 255) / 256, 256, 0, stream>>>(q_feat, q_pos, ws_q, Mq * C_ / 4);
  // value = src @ Wv + bv
  gemm_f32<false><<<dim3((Mv + 63) / 64, C_ / 64), 256, 0, stream>>>(src, Wv, bv, ws_val, Mv, C_, C_);
  // off = q @ Woff + boff
  gemm_f32<false><<<dim3((Mq + 63) / 64, C_ / 64), 256, 0, stream>>>(ws_q, Woff, boff, ws_off, Mq, C_, C_);
  // attn logits = q @ Wa + ba
  gemm_f32<false><<<dim3((Mq + 63) / 64, 128 / 64), 256, 0, stream>>>(ws_q, Wa, ba, ws_att, Mq, 128, C_);
  // softmax over groups of 16
  softmax16_kernel<<<(Mq * NH_ + 255) / 256, 256, 0, stream>>>(ws_att, Mq * NH_);
  // deformable sampling -> ms [B*NQ, 256]
  msdeform_kernel<<<(Mq * NH_ * DH_) / 256, 256, 0, stream>>>(ws_val, ws_off, ws_att, q_ref, vr, ws_ms);
  // a = ms @ Wo + bo
  gemm_f32<false><<<dim3((Mq + 63) / 64, C_ / 64), 256, 0, stream>>>(ws_ms, Wo, bo, ws_a, Mq, C_, C_);
  // x = LN(q_feat + a)
  add_ln_kernel<<<(Mq + 3) / 4, 256, 0, stream>>>(q_feat, ws_a, g1, be1, ws_x, Mq);
  // h1 = relu(x @ W1 + bf1)
  gemm_f32<true><<<dim3((Mq + 63) / 64, DFF_ / 64), 256, 0, stream>>>(ws_x, W1, bf1, ws_h1, Mq, DFF_, C_);
  // f2 = h1 @ W2 + bf2
  gemm_f32<false><<<dim3((Mq + 63) / 64, C_ / 64), 256, 0, stream>>>(ws_h1, W2, bf2, ws_f2, Mq, C_, DFF_);
  // out = LN(x + f2)
  add_ln_kernel<<<(Mq + 3) / 4, 256, 0, stream>>>(ws_x, ws_f2, g2, be2, outp, Mq);
}

// Round 2
// 277.759 us; speedup vs baseline: 3.0753x; 3.0753x over previous
//
#include <hip/hip_runtime.h>
#include <hip/hip_bf16.h>
#include <cstdint>

#define B_   2
#define NQ_  10000
#define C_   256
#define NH_  8
#define DH_  32
#define DFF_ 1024
#define S_   19560
#define MQ_P 20096   // 157*128
#define MV_P 39168   // 306*128

typedef __attribute__((ext_vector_type(8))) short short8;
typedef __attribute__((ext_vector_type(4))) float f32x4;

__device__ __forceinline__ void gload16(const void* g, void* l) {
  __builtin_amdgcn_global_load_lds(
      (const __attribute__((address_space(1))) unsigned int*)g,
      (__attribute__((address_space(3))) unsigned int*)l, 16, 0, 0);
}

__device__ __forceinline__ float bflo(unsigned u) {
  union { unsigned u; float f; } c; c.u = u << 16; return c.f;
}
__device__ __forceinline__ float bfhi(unsigned u) {
  union { unsigned u; float f; } c; c.u = u & 0xffff0000u; return c.f;
}

// ------------------------------------------------------------- weight conv+T
// Wt[n][k] = bf16(W[k][n]) for all six weights, packed at wbase.
__global__ __launch_bounds__(256) void conv_weights(
    const float* __restrict__ Wv, const float* __restrict__ Woff,
    const float* __restrict__ Wa, const float* __restrict__ Wo,
    const float* __restrict__ W1, const float* __restrict__ W2,
    __hip_bfloat16* __restrict__ wbase) {
  int idx = blockIdx.x * 256 + threadIdx.x;
  const float* W; __hip_bfloat16* Wt; int K, N, local;
  if (idx < 65536)        { W = Wv;   Wt = wbase + 0;      K = 256;  N = 256;  local = idx; }
  else if (idx < 131072)  { W = Woff; Wt = wbase + 65536;  K = 256;  N = 256;  local = idx - 65536; }
  else if (idx < 196608)  { W = Wo;   Wt = wbase + 131072; K = 256;  N = 256;  local = idx - 131072; }
  else if (idx < 229376)  { W = Wa;   Wt = wbase + 196608; K = 256;  N = 128;  local = idx - 196608; }
  else if (idx < 491520)  { W = W1;   Wt = wbase + 229376; K = 256;  N = 1024; local = idx - 229376; }
  else if (idx < 753664)  { W = W2;   Wt = wbase + 491520; K = 1024; N = 256;  local = idx - 491520; }
  else return;
  int k = local % K, n = local / K;
  Wt[(long)n * K + k] = __float2bfloat16(W[(long)k * N + n]);
}

// ------------------------------------------------------------- f32 -> bf16 pad
__global__ __launch_bounds__(256) void conv_pad(const float* __restrict__ in,
                                                __hip_bfloat16* __restrict__ out,
                                                int rows_real) {
  int idx = blockIdx.x * 256 + threadIdx.x;   // one per 8 elems, cols=256
  int row = idx >> 5, c8 = (idx & 31) * 8;
  union { __hip_bfloat16 h[8]; uint4 u; } o;
  if (row < rows_real) {
    const float4 a = *reinterpret_cast<const float4*>(in + (long)row * 256 + c8);
    const float4 b = *reinterpret_cast<const float4*>(in + (long)row * 256 + c8 + 4);
    o.h[0] = __float2bfloat16(a.x); o.h[1] = __float2bfloat16(a.y);
    o.h[2] = __float2bfloat16(a.z); o.h[3] = __float2bfloat16(a.w);
    o.h[4] = __float2bfloat16(b.x); o.h[5] = __float2bfloat16(b.y);
    o.h[6] = __float2bfloat16(b.z); o.h[7] = __float2bfloat16(b.w);
  } else {
    o.u = make_uint4(0, 0, 0, 0);
  }
  *reinterpret_cast<uint4*>(out + (long)row * 256 + c8) = o.u;
}

// q = bf16(q_feat + q_pos), padded
__global__ __launch_bounds__(256) void addq_bf16(const float* __restrict__ a,
                                                 const float* __restrict__ b,
                                                 __hip_bfloat16* __restrict__ out,
                                                 int rows_real) {
  int idx = blockIdx.x * 256 + threadIdx.x;
  int row = idx >> 5, c8 = (idx & 31) * 8;
  union { __hip_bfloat16 h[8]; uint4 u; } o;
  if (row < rows_real) {
    const float4 a0 = *reinterpret_cast<const float4*>(a + (long)row * 256 + c8);
    const float4 a1 = *reinterpret_cast<const float4*>(a + (long)row * 256 + c8 + 4);
    const float4 b0 = *reinterpret_cast<const float4*>(b + (long)row * 256 + c8);
    const float4 b1 = *reinterpret_cast<const float4*>(b + (long)row * 256 + c8 + 4);
    o.h[0] = __float2bfloat16(a0.x + b0.x); o.h[1] = __float2bfloat16(a0.y + b0.y);
    o.h[2] = __float2bfloat16(a0.z + b0.z); o.h[3] = __float2bfloat16(a0.w + b0.w);
    o.h[4] = __float2bfloat16(a1.x + b1.x); o.h[5] = __float2bfloat16(a1.y + b1.y);
    o.h[6] = __float2bfloat16(a1.z + b1.z); o.h[7] = __float2bfloat16(a1.w + b1.w);
  } else {
    o.u = make_uint4(0, 0, 0, 0);
  }
  *reinterpret_cast<uint4*>(out + (long)row * 256 + c8) = o.u;
}

// ------------------------------------------------------------- MFMA GEMM
// C[M,N] = A[M,K] @ Bt[N,K]^T + bias. A,Bt bf16 row-major. M multiple of 128,
// N multiple of 128, K multiple of 32.
// MODE 0: f32 row-major out. MODE 2: bf16 row-major out + ReLU.
// MODE 3: bf16 scatter to value layout [B][NH][S][DH], guard row < Mreal.
template <int MODE>
__global__ __launch_bounds__(256) void gemm_bf16(
    const __hip_bfloat16* __restrict__ A, const __hip_bfloat16* __restrict__ Bt,
    const float* __restrict__ bias, void* __restrict__ Cp,
    int M, int N, int K, int Mreal) {
  __shared__ short smA[128 * 32];
  __shared__ short smB[128 * 32];
  const int tid = threadIdx.x;
  const int lane = tid & 63;
  const int w = tid >> 6;
  const int wr = w >> 1, wc = w & 1;
  const long bm = (long)blockIdx.x * 128;
  const long bn = (long)blockIdx.y * 128;

  f32x4 acc[4][4];
#pragma unroll
  for (int i = 0; i < 4; ++i)
#pragma unroll
    for (int j = 0; j < 4; ++j) acc[i][j] = (f32x4)(0.f);

  const __hip_bfloat16* Ag = A + (bm + (tid >> 2)) * (long)K + (tid & 3) * 8;
  const __hip_bfloat16* Bg = Bt + (bn + (tid >> 2)) * (long)K + (tid & 3) * 8;
  char* lA = (char*)&smA[0] + tid * 16;
  char* lB = (char*)&smB[0] + tid * 16;

  const int arow = wr * 64 + (lane & 15);
  const int brow = wc * 64 + (lane & 15);
  const int koff = (lane >> 4) * 8;

  for (int k0 = 0; k0 < K; k0 += 32) {
    gload16(Ag,            lA);
    gload16(Ag + 64L * K,  lA + 4096);
    gload16(Bg,            lB);
    gload16(Bg + 64L * K,  lB + 4096);
    Ag += 32; Bg += 32;
    __syncthreads();
    short8 af[4], bf[4];
#pragma unroll
    for (int i = 0; i < 4; ++i)
      af[i] = *reinterpret_cast<const short8*>(&smA[(arow + i * 16) * 32 + koff]);
#pragma unroll
    for (int i = 0; i < 4; ++i)
      bf[i] = *reinterpret_cast<const short8*>(&smB[(brow + i * 16) * 32 + koff]);
#pragma unroll
    for (int mi = 0; mi < 4; ++mi)
#pragma unroll
      for (int ni = 0; ni < 4; ++ni)
        acc[mi][ni] = __builtin_amdgcn_mfma_f32_16x16x32_bf16(af[mi], bf[ni], acc[mi][ni], 0, 0, 0);
    __syncthreads();
  }

  const int crow0 = wr * 64 + ((lane >> 4) << 2);
  const int ccol0 = wc * 64 + (lane & 15);
#pragma unroll
  for (int mi = 0; mi < 4; ++mi) {
#pragma unroll
    for (int ni = 0; ni < 4; ++ni) {
      const int col = bn + ccol0 + ni * 16;
      const float bs = bias[col];
#pragma unroll
      for (int r = 0; r < 4; ++r) {
        const long row = bm + crow0 + mi * 16 + r;
        float v = acc[mi][ni][r] + bs;
        if (MODE == 0) {
          ((float*)Cp)[row * N + col] = v;
        } else if (MODE == 2) {
          ((__hip_bfloat16*)Cp)[row * N + col] = __float2bfloat16(fmaxf(v, 0.f));
        } else { // MODE 3: value scatter [B][NH][S][DH]
          if (row < Mreal) {
            const int b = (row >= S_) ? 1 : 0;
            const long s = row - (long)b * S_;
            const int h = col >> 5, dh = col & 31;
            ((__hip_bfloat16*)Cp)[(((long)(b * 8 + h)) * S_ + s) * 32 + dh] = __float2bfloat16(v);
          }
        }
      }
    }
  }
}

// ------------------------------------------------------------- softmax(16)
__global__ __launch_bounds__(256) void softmax16_kernel(float* __restrict__ attn, int n) {
  int i = blockIdx.x * 256 + threadIdx.x;
  if (i >= n) return;
  float* p = attn + (long)i * 16;
  float v[16];
#pragma unroll
  for (int j = 0; j < 4; ++j) {
    float4 t = reinterpret_cast<const float4*>(p)[j];
    v[j * 4 + 0] = t.x; v[j * 4 + 1] = t.y; v[j * 4 + 2] = t.z; v[j * 4 + 3] = t.w;
  }
  float m = v[0];
#pragma unroll
  for (int j = 1; j < 16; ++j) m = fmaxf(m, v[j]);
  float s = 0.f;
#pragma unroll
  for (int j = 0; j < 16; ++j) { v[j] = expf(v[j] - m); s += v[j]; }
  float inv = 1.f / s;
#pragma unroll
  for (int j = 0; j < 4; ++j) {
    float4 t;
    t.x = v[j * 4 + 0] * inv; t.y = v[j * 4 + 1] * inv;
    t.z = v[j * 4 + 2] * inv; t.w = v[j * 4 + 3] * inv;
    reinterpret_cast<float4*>(p)[j] = t;
  }
}

// ------------------------------------------------------------- ms_deform
// value bf16 [B][NH][S][32]; out bf16 [MQ_P][256] rows<20000.
// thread: dq=t&3 (8 channels), h=(t>>2)&7, bq=t>>5.
__global__ __launch_bounds__(256) void msdeform_kernel(
    const __hip_bfloat16* __restrict__ value, const float* __restrict__ off,
    const float* __restrict__ attn, const float* __restrict__ q_ref,
    const float* __restrict__ vr, __hip_bfloat16* __restrict__ out) {
  const int LVL_H[4] = {92, 46, 23, 12};
  const int LVL_W[4] = {160, 80, 40, 20};
  const int LVL_S[4] = {0, 14720, 18400, 19320};

  int t = blockIdx.x * 256 + threadIdx.x;
  int dq = t & 3;
  int h = (t >> 2) & 7;
  int bq = t >> 5;
  int b = (bq >= NQ_) ? 1 : 0;

  float rx = q_ref[(long)bq * 2 + 0];
  float ry = q_ref[(long)bq * 2 + 1];
  const float* offp = off + (long)bq * 256 + h * 32;
  const float* attp = attn + (long)bq * 128 + h * 16;
  float acc[8] = {};

#pragma unroll
  for (int l = 0; l < 4; ++l) {
    const int H = LVL_H[l], W = LVL_W[l];
    float vrx = vr[(b * 4 + l) * 2 + 0];
    float vry = vr[(b * 4 + l) * 2 + 1];
    float refxW = rx * vrx * W - 0.5f;
    float refyH = ry * vry * H - 0.5f;
    const __hip_bfloat16* vb = value + (((long)(b * 8 + h)) * S_ + LVL_S[l]) * 32 + dq * 8;
#pragma unroll
    for (int p = 0; p < 4; ++p) {
      float x = refxW + offp[(l * 4 + p) * 2 + 0];
      float y = refyH + offp[(l * 4 + p) * 2 + 1];
      float aw = attp[l * 4 + p];
      float x0f = floorf(x), y0f = floorf(y);
      float lx = x - x0f, ly = y - y0f;
      int x0 = (int)x0f, y0 = (int)y0f;
      float w00 = aw * (1.f - lx) * (1.f - ly);
      float w10 = aw * lx * (1.f - ly);
      float w01 = aw * (1.f - lx) * ly;
      float w11 = aw * lx * ly;
#define CORNER(xi, yi, wgt)                                                       \
      if ((unsigned)(xi) < (unsigned)W && (unsigned)(yi) < (unsigned)H) {         \
        const uint4 vv = *reinterpret_cast<const uint4*>(vb + ((long)(yi) * W + (xi)) * 32); \
        const float ww = (wgt);                                                   \
        acc[0] += ww * bflo(vv.x); acc[1] += ww * bfhi(vv.x);                     \
        acc[2] += ww * bflo(vv.y); acc[3] += ww * bfhi(vv.y);                     \
        acc[4] += ww * bflo(vv.z); acc[5] += ww * bfhi(vv.z);                     \
        acc[6] += ww * bflo(vv.w); acc[7] += ww * bfhi(vv.w);                     \
      }
      CORNER(x0,     y0,     w00)
      CORNER(x0 + 1, y0,     w10)
      CORNER(x0,     y0 + 1, w01)
      CORNER(x0 + 1, y0 + 1, w11)
#undef CORNER
    }
  }
  union { __hip_bfloat16 hh[8]; uint4 u; } o;
#pragma unroll
  for (int j = 0; j < 8; ++j) o.hh[j] = __float2bfloat16(acc[j]);
  *reinterpret_cast<uint4*>(out + (long)bq * 256 + h * 32 + dq * 8) = o.u;
}

// ------------------------------------------------------------- residual+LN
__global__ __launch_bounds__(256) void add_ln_kernel(
    const float* __restrict__ res, const float* __restrict__ xin,
    const float* __restrict__ gamma, const float* __restrict__ beta,
    float* __restrict__ out, __hip_bfloat16* __restrict__ out_bf, int nrows) {
  int row = blockIdx.x * 4 + (threadIdx.x >> 6);
  int lane = threadIdx.x & 63;
  if (row >= nrows) return;
  const float4 r4 = *reinterpret_cast<const float4*>(res + (long)row * 256 + lane * 4);
  const float4 x4 = *reinterpret_cast<const float4*>(xin + (long)row * 256 + lane * 4);
  float tv[4] = {r4.x + x4.x, r4.y + x4.y, r4.z + x4.z, r4.w + x4.w};
  float s = tv[0] + tv[1] + tv[2] + tv[3];
#pragma unroll
  for (int o = 32; o > 0; o >>= 1) s += __shfl_xor(s, o, 64);
  float mean = s * (1.f / 256.f);
  float vs = 0.f;
#pragma unroll
  for (int j = 0; j < 4; ++j) { float dd = tv[j] - mean; vs += dd * dd; }
#pragma unroll
  for (int o = 32; o > 0; o >>= 1) vs += __shfl_xor(vs, o, 64);
  float inv = rsqrtf(vs * (1.f / 256.f) + 1e-5f);
  const float4 g = *reinterpret_cast<const float4*>(gamma + lane * 4);
  const float4 be = *reinterpret_cast<const float4*>(beta + lane * 4);
  float4 o4;
  o4.x = (tv[0] - mean) * inv * g.x + be.x;
  o4.y = (tv[1] - mean) * inv * g.y + be.y;
  o4.z = (tv[2] - mean) * inv * g.z + be.z;
  o4.w = (tv[3] - mean) * inv * g.w + be.w;
  *reinterpret_cast<float4*>(out + (long)row * 256 + lane * 4) = o4;
  if (out_bf) {
    union { __hip_bfloat16 h[4]; uint2 u; } p;
    p.h[0] = __float2bfloat16(o4.x); p.h[1] = __float2bfloat16(o4.y);
    p.h[2] = __float2bfloat16(o4.z); p.h[3] = __float2bfloat16(o4.w);
    *reinterpret_cast<uint2*>(out_bf + (long)row * 256 + lane * 4) = p.u;
  }
}

// ------------------------------------------------------------- launch
extern "C" void kernel_launch(void* const* d_in, const int* in_sizes, int n_in,
                              void* d_out, int out_size, void* d_ws, size_t ws_size,
                              hipStream_t stream) {
  const float* src    = (const float*)d_in[0];
  const float* q_feat = (const float*)d_in[1];
  const float* q_pos  = (const float*)d_in[2];
  const float* q_ref  = (const float*)d_in[3];
  const float* vr     = (const float*)d_in[4];
  const float* Wv     = (const float*)d_in[5];
  const float* bv     = (const float*)d_in[6];
  const float* Woff   = (const float*)d_in[7];
  const float* boff   = (const float*)d_in[8];
  const float* Wa     = (const float*)d_in[9];
  const float* ba     = (const float*)d_in[10];
  const float* Wo     = (const float*)d_in[11];
  const float* bo     = (const float*)d_in[12];
  const float* g1     = (const float*)d_in[13];
  const float* be1    = (const float*)d_in[14];
  const float* W1     = (const float*)d_in[15];
  const float* bf1    = (const float*)d_in[16];
  const float* W2     = (const float*)d_in[17];
  const float* bf2    = (const float*)d_in[18];
  const float* g2     = (const float*)d_in[19];
  const float* be2    = (const float*)d_in[20];

  char* ws = (char*)d_ws;
  // region plan (bytes), with lifetime-based reuse:
  __hip_bfloat16* src_bf = (__hip_bfloat16*)(ws + 0);          // 20,054,016
  float*          a_f    = (float*)(ws + 0);                   // reuse after value GEMM
  __hip_bfloat16* q_bf   = (__hip_bfloat16*)(ws + 20578304);   // 10,289,152
  __hip_bfloat16* val_bf = (__hip_bfloat16*)(ws + 30867456);   // 20,029,440
  float*          off_f  = (float*)(ws + 50896896);            // 20,578,304
  __hip_bfloat16* h1_bf  = (__hip_bfloat16*)(ws + 20578304);   // reuse q/val/off after msdeform
  float*          attn_f = (float*)(ws + 71475200);            // 10,289,152
  __hip_bfloat16* ms_bf  = (__hip_bfloat16*)(ws + 81764352);   // 10,289,152
  float*          f2_f   = (float*)(ws + 71475200);            // reuse attn+ms after proj
  float*          x_f    = (float*)(ws + 92053504);            // 20,578,304
  __hip_bfloat16* x_bf   = (__hip_bfloat16*)(ws + 112631808);  // 10,289,152
  __hip_bfloat16* wts    = (__hip_bfloat16*)(ws + 122920960);  // 1,507,328
  float* outp = (float*)d_out;

  const int Mq = B_ * NQ_;   // 20000
  const int Mv = B_ * S_;    // 39120

  // weights -> bf16 transposed [N][K]
  conv_weights<<<2944, 256, 0, stream>>>(Wv, Woff, Wa, Wo, W1, W2, wts);
  // src -> bf16 padded
  conv_pad<<<MV_P * 32 / 256, 256, 0, stream>>>(src, src_bf, Mv);
  // q = bf16(q_feat + q_pos) padded
  addq_bf16<<<MQ_P * 32 / 256, 256, 0, stream>>>(q_feat, q_pos, q_bf, Mq);
  // value = src @ Wv + bv  -> bf16 scatter [B][NH][S][DH]
  gemm_bf16<3><<<dim3(MV_P / 128, 2), 256, 0, stream>>>(src_bf, wts + 0, bv, val_bf, MV_P, 256, 256, Mv);
  // off = q @ Woff + boff  (f32)
  gemm_bf16<0><<<dim3(MQ_P / 128, 2), 256, 0, stream>>>(q_bf, wts + 65536, boff, off_f, MQ_P, 256, 256, MQ_P);
  // attn logits = q @ Wa + ba  (f32)
  gemm_bf16<0><<<dim3(MQ_P / 128, 1), 256, 0, stream>>>(q_bf, wts + 196608, ba, attn_f, MQ_P, 128, 256, MQ_P);
  // softmax over groups of 16
  softmax16_kernel<<<(Mq * NH_) / 256, 256, 0, stream>>>(attn_f, Mq * NH_);
  // deformable sampling -> ms bf16
  msdeform_kernel<<<(Mq * 32) / 256, 256, 0, stream>>>(val_bf, off_f, attn_f, q_ref, vr, ms_bf);
  // a = ms @ Wo + bo  (f32)
  gemm_bf16<0><<<dim3(MQ_P / 128, 2), 256, 0, stream>>>(ms_bf, wts + 131072, bo, a_f, MQ_P, 256, 256, MQ_P);
  // x = LN(q_feat + a), plus bf16 copy
  add_ln_kernel<<<(Mq + 3) / 4, 256, 0, stream>>>(q_feat, a_f, g1, be1, x_f, x_bf, Mq);
  // h1 = relu(x @ W1 + bf1)  (bf16)
  gemm_bf16<2><<<dim3(MQ_P / 128, 8), 256, 0, stream>>>(x_bf, wts + 229376, bf1, h1_bf, MQ_P, 1024, 256, MQ_P);
  // f2 = h1 @ W2 + bf2  (f32)
  gemm_bf16<0><<<dim3(MQ_P / 128, 2), 256, 0, stream>>>(h1_bf, wts + 491520, bf2, f2_f, MQ_P, 256, 1024, MQ_P);
  // out = LN(x + f2)
  add_ln_kernel<<<(Mq + 3) / 4, 256, 0, stream>>>(x_f, f2_f, g2, be2, outp, nullptr, Mq);
}

// Round 3
// 224.063 us; speedup vs baseline: 3.8122x; 1.2396x over previous
//
#include <hip/hip_runtime.h>
#include <hip/hip_bf16.h>
#include <cstdint>

#define B_   2
#define NQ_  10000
#define C_   256
#define NH_  8
#define DH_  32
#define DFF_ 1024
#define S_   19560
#define MQ_P 20096   // 157*128
#define MV_P 39168   // 306*128

typedef __attribute__((ext_vector_type(8))) short short8;
typedef __attribute__((ext_vector_type(4))) float f32x4;

__device__ __forceinline__ void gload16(const void* g, void* l) {
  __builtin_amdgcn_global_load_lds(
      (const __attribute__((address_space(1))) unsigned int*)g,
      (__attribute__((address_space(3))) unsigned int*)l, 16, 0, 0);
}

__device__ __forceinline__ float bflo(unsigned u) {
  union { unsigned u; float f; } c; c.u = u << 16; return c.f;
}
__device__ __forceinline__ float bfhi(unsigned u) {
  union { unsigned u; float f; } c; c.u = u & 0xffff0000u; return c.f;
}

// ------------------------------------------------------------- weight conv+T
// Wt[n][k] = bf16(W[k][n]) for all six weights, packed at wbase.
__global__ __launch_bounds__(256) void conv_weights(
    const float* __restrict__ Wv, const float* __restrict__ Woff,
    const float* __restrict__ Wa, const float* __restrict__ Wo,
    const float* __restrict__ W1, const float* __restrict__ W2,
    __hip_bfloat16* __restrict__ wbase) {
  int idx = blockIdx.x * 256 + threadIdx.x;
  const float* W; __hip_bfloat16* Wt; int K, N, local;
  if (idx < 65536)        { W = Wv;   Wt = wbase + 0;      K = 256;  N = 256;  local = idx; }
  else if (idx < 131072)  { W = Woff; Wt = wbase + 65536;  K = 256;  N = 256;  local = idx - 65536; }
  else if (idx < 196608)  { W = Wo;   Wt = wbase + 131072; K = 256;  N = 256;  local = idx - 131072; }
  else if (idx < 229376)  { W = Wa;   Wt = wbase + 196608; K = 256;  N = 128;  local = idx - 196608; }
  else if (idx < 491520)  { W = W1;   Wt = wbase + 229376; K = 256;  N = 1024; local = idx - 229376; }
  else if (idx < 753664)  { W = W2;   Wt = wbase + 491520; K = 1024; N = 256;  local = idx - 491520; }
  else return;
  int k = local % K, n = local / K;
  Wt[(long)n * K + k] = __float2bfloat16(W[(long)k * N + n]);
}

// ------------------------------------------------------------- f32 -> bf16 pad
__global__ __launch_bounds__(256) void conv_pad(const float* __restrict__ in,
                                                __hip_bfloat16* __restrict__ out,
                                                int rows_real) {
  int idx = blockIdx.x * 256 + threadIdx.x;   // one per 8 elems, cols=256
  int row = idx >> 5, c8 = (idx & 31) * 8;
  union { __hip_bfloat16 h[8]; uint4 u; } o;
  if (row < rows_real) {
    const float4 a = *reinterpret_cast<const float4*>(in + (long)row * 256 + c8);
    const float4 b = *reinterpret_cast<const float4*>(in + (long)row * 256 + c8 + 4);
    o.h[0] = __float2bfloat16(a.x); o.h[1] = __float2bfloat16(a.y);
    o.h[2] = __float2bfloat16(a.z); o.h[3] = __float2bfloat16(a.w);
    o.h[4] = __float2bfloat16(b.x); o.h[5] = __float2bfloat16(b.y);
    o.h[6] = __float2bfloat16(b.z); o.h[7] = __float2bfloat16(b.w);
  } else {
    o.u = make_uint4(0, 0, 0, 0);
  }
  *reinterpret_cast<uint4*>(out + (long)row * 256 + c8) = o.u;
}

// q = bf16(q_feat + q_pos), padded
__global__ __launch_bounds__(256) void addq_bf16(const float* __restrict__ a,
                                                 const float* __restrict__ b,
                                                 __hip_bfloat16* __restrict__ out,
                                                 int rows_real) {
  int idx = blockIdx.x * 256 + threadIdx.x;
  int row = idx >> 5, c8 = (idx & 31) * 8;
  union { __hip_bfloat16 h[8]; uint4 u; } o;
  if (row < rows_real) {
    const float4 a0 = *reinterpret_cast<const float4*>(a + (long)row * 256 + c8);
    const float4 a1 = *reinterpret_cast<const float4*>(a + (long)row * 256 + c8 + 4);
    const float4 b0 = *reinterpret_cast<const float4*>(b + (long)row * 256 + c8);
    const float4 b1 = *reinterpret_cast<const float4*>(b + (long)row * 256 + c8 + 4);
    o.h[0] = __float2bfloat16(a0.x + b0.x); o.h[1] = __float2bfloat16(a0.y + b0.y);
    o.h[2] = __float2bfloat16(a0.z + b0.z); o.h[3] = __float2bfloat16(a0.w + b0.w);
    o.h[4] = __float2bfloat16(a1.x + b1.x); o.h[5] = __float2bfloat16(a1.y + b1.y);
    o.h[6] = __float2bfloat16(a1.z + b1.z); o.h[7] = __float2bfloat16(a1.w + b1.w);
  } else {
    o.u = make_uint4(0, 0, 0, 0);
  }
  *reinterpret_cast<uint4*>(out + (long)row * 256 + c8) = o.u;
}

// ------------------------------------------------------------- MFMA GEMM
// C[M,N] = A[M,K] @ Bt[N,K]^T + bias. A,Bt bf16 row-major. M mult of 64,
// N mult of 128, K mult of 64. Tile 64x128, BK=64, 256 thr (2x2 waves).
// LDS XOR-swizzle: physical 16B slot p at row r holds logical k-unit p^(r&7);
// staged via pre-swizzled global source (linear LDS dest), read with same XOR.
// MODE 0: f32 row-major out. MODE 2: bf16 row-major out + ReLU.
// MODE 3: bf16 scatter to value layout [B][NH][S][DH], guard row < Mreal.
template <int MODE>
__global__ __launch_bounds__(256) void gemm_bf16(
    const __hip_bfloat16* __restrict__ A, const __hip_bfloat16* __restrict__ Bt,
    const float* __restrict__ bias, void* __restrict__ Cp,
    int M, int N, int K, int Mreal) {
  __shared__ short smA[64 * 64];    // 8KB
  __shared__ short smB[128 * 64];   // 16KB
  const int tid = threadIdx.x;
  const int lane = tid & 63;
  const int w = tid >> 6;
  const int wr = w >> 1, wc = w & 1;
  const long bm = (long)blockIdx.x * 64;
  const long bn = (long)blockIdx.y * 128;

  f32x4 acc[2][4];
#pragma unroll
  for (int i = 0; i < 2; ++i)
#pragma unroll
    for (int j = 0; j < 4; ++j) acc[i][j] = (f32x4)(0.f);

  const int srow = tid >> 3;                 // 0..31
  const int su = (tid & 7) ^ (srow & 7);     // logical k-unit for this lane
  const __hip_bfloat16* Ag = A + (bm + srow) * (long)K + su * 8;
  const __hip_bfloat16* Bg = Bt + (bn + srow) * (long)K + su * 8;
  char* lA = (char*)smA + tid * 16;
  char* lB = (char*)smB + tid * 16;

  for (int k0 = 0; k0 < K; k0 += 64) {
    gload16(Ag,           lA);
    gload16(Ag + 32L * K, lA + 4096);
    gload16(Bg,           lB);
    gload16(Bg + 32L * K, lB + 4096);
    gload16(Bg + 64L * K, lB + 8192);
    gload16(Bg + 96L * K, lB + 12288);
    Ag += 64; Bg += 64;
    __syncthreads();
#pragma unroll
    for (int ks = 0; ks < 2; ++ks) {
      const int u = ks * 4 + (lane >> 4);    // logical 16B unit (k-slot)
      short8 af[2], bf[4];
#pragma unroll
      for (int mi = 0; mi < 2; ++mi) {
        const int r = wr * 32 + (lane & 15) + mi * 16;
        af[mi] = *reinterpret_cast<const short8*>(
            (char*)smA + r * 128 + ((u ^ (r & 7)) * 16));
      }
#pragma unroll
      for (int ni = 0; ni < 4; ++ni) {
        const int r = wc * 64 + (lane & 15) + ni * 16;
        bf[ni] = *reinterpret_cast<const short8*>(
            (char*)smB + r * 128 + ((u ^ (r & 7)) * 16));
      }
#pragma unroll
      for (int mi = 0; mi < 2; ++mi)
#pragma unroll
        for (int ni = 0; ni < 4; ++ni)
          acc[mi][ni] = __builtin_amdgcn_mfma_f32_16x16x32_bf16(af[mi], bf[ni], acc[mi][ni], 0, 0, 0);
    }
    __syncthreads();
  }

  const int crow0 = wr * 32 + ((lane >> 4) << 2);
  const int ccol0 = wc * 64 + (lane & 15);
#pragma unroll
  for (int mi = 0; mi < 2; ++mi) {
#pragma unroll
    for (int ni = 0; ni < 4; ++ni) {
      const int col = bn + ccol0 + ni * 16;
      const float bs = bias[col];
#pragma unroll
      for (int r = 0; r < 4; ++r) {
        const long row = bm + crow0 + mi * 16 + r;
        float v = acc[mi][ni][r] + bs;
        if (MODE == 0) {
          ((float*)Cp)[row * N + col] = v;
        } else if (MODE == 2) {
          ((__hip_bfloat16*)Cp)[row * N + col] = __float2bfloat16(fmaxf(v, 0.f));
        } else { // MODE 3: value scatter [B][NH][S][DH]
          if (row < Mreal) {
            const int b = (row >= S_) ? 1 : 0;
            const long s = row - (long)b * S_;
            const int h = col >> 5, dh = col & 31;
            ((__hip_bfloat16*)Cp)[(((long)(b * 8 + h)) * S_ + s) * 32 + dh] = __float2bfloat16(v);
          }
        }
      }
    }
  }
}

// ------------------------------------------------------------- ms_deform
// value bf16 [B][NH][S][32]; logits f32 [bq][128] (pre-softmax);
// out bf16 [MQ_P][256] rows<20000. Thread: dq=t&1 (16 ch), h=(t>>1)&7, bq=t>>4.
// Branchless zero-pad bilinear: per-axis validity folded into weights,
// clamped always-executed loads. Softmax over 16 fused in.
__global__ __launch_bounds__(256) void msdeform_kernel(
    const __hip_bfloat16* __restrict__ value, const float* __restrict__ off,
    const float* __restrict__ logits, const float* __restrict__ q_ref,
    const float* __restrict__ vr, __hip_bfloat16* __restrict__ out) {
  const int LVL_H[4] = {92, 46, 23, 12};
  const int LVL_W[4] = {160, 80, 40, 20};
  const int LVL_S[4] = {0, 14720, 18400, 19320};

  const int t = blockIdx.x * 256 + threadIdx.x;
  const int dq = t & 1;
  const int h = (t >> 1) & 7;
  const int bq = t >> 4;
  const int b = (bq >= NQ_) ? 1 : 0;

  // fused softmax over the 16 (l,p) logits
  const float* lg = logits + (long)bq * 128 + h * 16;
  float wgt[16];
#pragma unroll
  for (int j = 0; j < 4; ++j) {
    float4 v = reinterpret_cast<const float4*>(lg)[j];
    wgt[j * 4 + 0] = v.x; wgt[j * 4 + 1] = v.y;
    wgt[j * 4 + 2] = v.z; wgt[j * 4 + 3] = v.w;
  }
  float mx = wgt[0];
#pragma unroll
  for (int j = 1; j < 16; ++j) mx = fmaxf(mx, wgt[j]);
  float sum = 0.f;
#pragma unroll
  for (int j = 0; j < 16; ++j) { wgt[j] = __expf(wgt[j] - mx); sum += wgt[j]; }
  const float inv = 1.f / sum;
#pragma unroll
  for (int j = 0; j < 16; ++j) wgt[j] *= inv;

  const float rx = q_ref[(long)bq * 2 + 0];
  const float ry = q_ref[(long)bq * 2 + 1];
  const float* offp = off + (long)bq * 256 + h * 32;
  float acc[16] = {};

#pragma unroll
  for (int l = 0; l < 4; ++l) {
    const int W = LVL_W[l], H = LVL_H[l];
    const float vrx = vr[(b * 4 + l) * 2 + 0];
    const float vry = vr[(b * 4 + l) * 2 + 1];
    const float refxW = rx * vrx * W - 0.5f;
    const float refyH = ry * vry * H - 0.5f;
    const __hip_bfloat16* vb = value + (((long)(b * 8 + h)) * S_ + LVL_S[l]) * 32 + dq * 16;
#pragma unroll
    for (int p = 0; p < 4; ++p) {
      const float x = refxW + offp[(l * 4 + p) * 2 + 0];
      const float y = refyH + offp[(l * 4 + p) * 2 + 1];
      const float aw = wgt[l * 4 + p];
      const float x0f = floorf(x), y0f = floorf(y);
      const float lx = x - x0f, ly = y - y0f;
      const int x0 = (int)x0f, y0 = (int)y0f;
      const int x1 = x0 + 1, y1 = y0 + 1;
      const float wx0 = ((unsigned)x0 < (unsigned)W) ? (1.f - lx) : 0.f;
      const float wx1 = ((unsigned)x1 < (unsigned)W) ? lx : 0.f;
      const float wy0 = ((unsigned)y0 < (unsigned)H) ? (1.f - ly) : 0.f;
      const float wy1 = ((unsigned)y1 < (unsigned)H) ? ly : 0.f;
      const int x0c = min(max(x0, 0), W - 1);
      const int x1c = min(max(x1, 0), W - 1);
      const int y0c = min(max(y0, 0), H - 1);
      const int y1c = min(max(y1, 0), H - 1);
      const long i00 = (long)(y0c * W + x0c) * 32;
      const long i10 = (long)(y0c * W + x1c) * 32;
      const long i01 = (long)(y1c * W + x0c) * 32;
      const long i11 = (long)(y1c * W + x1c) * 32;
      const float w00 = aw * wx0 * wy0, w10 = aw * wx1 * wy0;
      const float w01 = aw * wx0 * wy1, w11 = aw * wx1 * wy1;
      const uint4 a0 = *reinterpret_cast<const uint4*>(vb + i00);
      const uint4 a1 = *reinterpret_cast<const uint4*>(vb + i00 + 8);
      const uint4 b0 = *reinterpret_cast<const uint4*>(vb + i10);
      const uint4 b1 = *reinterpret_cast<const uint4*>(vb + i10 + 8);
      const uint4 c0 = *reinterpret_cast<const uint4*>(vb + i01);
      const uint4 c1 = *reinterpret_cast<const uint4*>(vb + i01 + 8);
      const uint4 d0 = *reinterpret_cast<const uint4*>(vb + i11);
      const uint4 d1 = *reinterpret_cast<const uint4*>(vb + i11 + 8);
#define ACC8(vv, ww, base)                                        \
      acc[base + 0] += ww * bflo(vv.x); acc[base + 1] += ww * bfhi(vv.x); \
      acc[base + 2] += ww * bflo(vv.y); acc[base + 3] += ww * bfhi(vv.y); \
      acc[base + 4] += ww * bflo(vv.z); acc[base + 5] += ww * bfhi(vv.z); \
      acc[base + 6] += ww * bflo(vv.w); acc[base + 7] += ww * bfhi(vv.w);
      ACC8(a0, w00, 0) ACC8(a1, w00, 8)
      ACC8(b0, w10, 0) ACC8(b1, w10, 8)
      ACC8(c0, w01, 0) ACC8(c1, w01, 8)
      ACC8(d0, w11, 0) ACC8(d1, w11, 8)
#undef ACC8
    }
  }
  union { __hip_bfloat16 hh[8]; uint4 u; } o0, o1;
#pragma unroll
  for (int j = 0; j < 8; ++j) {
    o0.hh[j] = __float2bfloat16(acc[j]);
    o1.hh[j] = __float2bfloat16(acc[j + 8]);
  }
  __hip_bfloat16* op = out + (long)bq * 256 + h * 32 + dq * 16;
  *reinterpret_cast<uint4*>(op) = o0.u;
  *reinterpret_cast<uint4*>(op + 8) = o1.u;
}

// ------------------------------------------------------------- residual+LN
__global__ __launch_bounds__(256) void add_ln_kernel(
    const float* __restrict__ res, const float* __restrict__ xin,
    const float* __restrict__ gamma, const float* __restrict__ beta,
    float* __restrict__ out, __hip_bfloat16* __restrict__ out_bf, int nrows) {
  int row = blockIdx.x * 4 + (threadIdx.x >> 6);
  int lane = threadIdx.x & 63;
  if (row >= nrows) return;
  const float4 r4 = *reinterpret_cast<const float4*>(res + (long)row * 256 + lane * 4);
  const float4 x4 = *reinterpret_cast<const float4*>(xin + (long)row * 256 + lane * 4);
  float tv[4] = {r4.x + x4.x, r4.y + x4.y, r4.z + x4.z, r4.w + x4.w};
  float s = tv[0] + tv[1] + tv[2] + tv[3];
#pragma unroll
  for (int o = 32; o > 0; o >>= 1) s += __shfl_xor(s, o, 64);
  float mean = s * (1.f / 256.f);
  float vs = 0.f;
#pragma unroll
  for (int j = 0; j < 4; ++j) { float dd = tv[j] - mean; vs += dd * dd; }
#pragma unroll
  for (int o = 32; o > 0; o >>= 1) vs += __shfl_xor(vs, o, 64);
  float inv = rsqrtf(vs * (1.f / 256.f) + 1e-5f);
  const float4 g = *reinterpret_cast<const float4*>(gamma + lane * 4);
  const float4 be = *reinterpret_cast<const float4*>(beta + lane * 4);
  float4 o4;
  o4.x = (tv[0] - mean) * inv * g.x + be.x;
  o4.y = (tv[1] - mean) * inv * g.y + be.y;
  o4.z = (tv[2] - mean) * inv * g.z + be.z;
  o4.w = (tv[3] - mean) * inv * g.w + be.w;
  *reinterpret_cast<float4*>(out + (long)row * 256 + lane * 4) = o4;
  if (out_bf) {
    union { __hip_bfloat16 h[4]; uint2 u; } p;
    p.h[0] = __float2bfloat16(o4.x); p.h[1] = __float2bfloat16(o4.y);
    p.h[2] = __float2bfloat16(o4.z); p.h[3] = __float2bfloat16(o4.w);
    *reinterpret_cast<uint2*>(out_bf + (long)row * 256 + lane * 4) = p.u;
  }
}

// ------------------------------------------------------------- launch
extern "C" void kernel_launch(void* const* d_in, const int* in_sizes, int n_in,
                              void* d_out, int out_size, void* d_ws, size_t ws_size,
                              hipStream_t stream) {
  const float* src    = (const float*)d_in[0];
  const float* q_feat = (const float*)d_in[1];
  const float* q_pos  = (const float*)d_in[2];
  const float* q_ref  = (const float*)d_in[3];
  const float* vr     = (const float*)d_in[4];
  const float* Wv     = (const float*)d_in[5];
  const float* bv     = (const float*)d_in[6];
  const float* Woff   = (const float*)d_in[7];
  const float* boff   = (const float*)d_in[8];
  const float* Wa     = (const float*)d_in[9];
  const float* ba     = (const float*)d_in[10];
  const float* Wo     = (const float*)d_in[11];
  const float* bo     = (const float*)d_in[12];
  const float* g1     = (const float*)d_in[13];
  const float* be1    = (const float*)d_in[14];
  const float* W1     = (const float*)d_in[15];
  const float* bf1    = (const float*)d_in[16];
  const float* W2     = (const float*)d_in[17];
  const float* bf2    = (const float*)d_in[18];
  const float* g2     = (const float*)d_in[19];
  const float* be2    = (const float*)d_in[20];

  char* ws = (char*)d_ws;
  __hip_bfloat16* src_bf = (__hip_bfloat16*)(ws + 0);          // 20,054,016
  float*          a_f    = (float*)(ws + 0);                   // reuse after value GEMM
  __hip_bfloat16* q_bf   = (__hip_bfloat16*)(ws + 20578304);   // 10,289,152
  __hip_bfloat16* val_bf = (__hip_bfloat16*)(ws + 30867456);   // 20,029,440
  float*          off_f  = (float*)(ws + 50896896);            // 20,578,304
  __hip_bfloat16* h1_bf  = (__hip_bfloat16*)(ws + 20578304);   // reuse q/val/off after msdeform
  float*          attn_f = (float*)(ws + 71475200);            // 10,289,152 (logits)
  __hip_bfloat16* ms_bf  = (__hip_bfloat16*)(ws + 81764352);   // 10,289,152
  float*          f2_f   = (float*)(ws + 71475200);            // reuse attn+ms after proj
  float*          x_f    = (float*)(ws + 92053504);            // 20,578,304
  __hip_bfloat16* x_bf   = (__hip_bfloat16*)(ws + 112631808);  // 10,289,152
  __hip_bfloat16* wts    = (__hip_bfloat16*)(ws + 122920960);  // 1,507,328
  float* outp = (float*)d_out;

  const int Mq = B_ * NQ_;   // 20000
  const int Mv = B_ * S_;    // 39120

  // weights -> bf16 transposed [N][K]
  conv_weights<<<2944, 256, 0, stream>>>(Wv, Woff, Wa, Wo, W1, W2, wts);
  // src -> bf16 padded
  conv_pad<<<MV_P * 32 / 256, 256, 0, stream>>>(src, src_bf, Mv);
  // q = bf16(q_feat + q_pos) padded
  addq_bf16<<<MQ_P * 32 / 256, 256, 0, stream>>>(q_feat, q_pos, q_bf, Mq);
  // value = src @ Wv + bv  -> bf16 scatter [B][NH][S][DH]
  gemm_bf16<3><<<dim3(MV_P / 64, 2), 256, 0, stream>>>(src_bf, wts + 0, bv, val_bf, MV_P, 256, 256, Mv);
  // off = q @ Woff + boff  (f32)
  gemm_bf16<0><<<dim3(MQ_P / 64, 2), 256, 0, stream>>>(q_bf, wts + 65536, boff, off_f, MQ_P, 256, 256, MQ_P);
  // attn logits = q @ Wa + ba  (f32) — softmax fused into msdeform
  gemm_bf16<0><<<dim3(MQ_P / 64, 1), 256, 0, stream>>>(q_bf, wts + 196608, ba, attn_f, MQ_P, 128, 256, MQ_P);
  // deformable sampling -> ms bf16
  msdeform_kernel<<<(Mq * 16) / 256, 256, 0, stream>>>(val_bf, off_f, attn_f, q_ref, vr, ms_bf);
  // a = ms @ Wo + bo  (f32)
  gemm_bf16<0><<<dim3(MQ_P / 64, 2), 256, 0, stream>>>(ms_bf, wts + 131072, bo, a_f, MQ_P, 256, 256, MQ_P);
  // x = LN(q_feat + a), plus bf16 copy
  add_ln_kernel<<<(Mq + 3) / 4, 256, 0, stream>>>(q_feat, a_f, g1, be1, x_f, x_bf, Mq);
  // h1 = relu(x @ W1 + bf1)  (bf16)
  gemm_bf16<2><<<dim3(MQ_P / 64, 8), 256, 0, stream>>>(x_bf, wts + 229376, bf1, h1_bf, MQ_P, 1024, 256, MQ_P);
  // f2 = h1 @ W2 + bf2  (f32)
  gemm_bf16<0><<<dim3(MQ_P / 64, 2), 256, 0, stream>>>(h1_bf, wts + 491520, bf2, f2_f, MQ_P, 256, 1024, MQ_P);
  // out = LN(x + f2)
  add_ln_kernel<<<(Mq + 3) / 4, 256, 0, stream>>>(x_f, f2_f, g2, be2, outp, Mq ? nullptr : nullptr, Mq);
}

// Round 4
// 215.163 us; speedup vs baseline: 3.9699x; 1.0414x over previous
//
#include <hip/hip_runtime.h>
#include <hip/hip_bf16.h>
#include <cstdint>

#define B_   2
#define NQ_  10000
#define C_   256
#define NH_  8
#define DH_  32
#define DFF_ 1024
#define S_   19560
#define MQ_P 20096   // 157*128
#define MV_P 39168   // 306*128

typedef __attribute__((ext_vector_type(8))) short short8;
typedef __attribute__((ext_vector_type(4))) float f32x4;

__device__ __forceinline__ void gload16(const void* g, void* l) {
  __builtin_amdgcn_global_load_lds(
      (const __attribute__((address_space(1))) unsigned int*)g,
      (__attribute__((address_space(3))) unsigned int*)l, 16, 0, 0);
}

__device__ __forceinline__ float bflo(unsigned u) {
  union { unsigned u; float f; } c; c.u = u << 16; return c.f;
}
__device__ __forceinline__ float bfhi(unsigned u) {
  union { unsigned u; float f; } c; c.u = u & 0xffff0000u; return c.f;
}

// ------------------------------------------------------------- weight conv+T
// Wt[n][k] = bf16(W[k][n]); layout: Wv | Woff | Wa | Wo | W1 | W2
// (Woff and Wa adjacent -> one [384][256] B-matrix for the merged GEMM)
__global__ __launch_bounds__(256) void conv_weights(
    const float* __restrict__ Wv, const float* __restrict__ Woff,
    const float* __restrict__ Wa, const float* __restrict__ Wo,
    const float* __restrict__ W1, const float* __restrict__ W2,
    __hip_bfloat16* __restrict__ wbase) {
  int idx = blockIdx.x * 256 + threadIdx.x;
  const float* W; __hip_bfloat16* Wt; int K, N, local;
  if (idx < 65536)        { W = Wv;   Wt = wbase + 0;      K = 256;  N = 256;  local = idx; }
  else if (idx < 131072)  { W = Woff; Wt = wbase + 65536;  K = 256;  N = 256;  local = idx - 65536; }
  else if (idx < 163840)  { W = Wa;   Wt = wbase + 131072; K = 256;  N = 128;  local = idx - 131072; }
  else if (idx < 229376)  { W = Wo;   Wt = wbase + 163840; K = 256;  N = 256;  local = idx - 163840; }
  else if (idx < 491520)  { W = W1;   Wt = wbase + 229376; K = 256;  N = 1024; local = idx - 229376; }
  else if (idx < 753664)  { W = W2;   Wt = wbase + 491520; K = 1024; N = 256;  local = idx - 491520; }
  else return;
  int k = local % K, n = local / K;
  Wt[(long)n * K + k] = __float2bfloat16(W[(long)k * N + n]);
}

// ------------------------------------------------------------- input prep
// part 1: src -> bf16 padded [MV_P][256]; part 2: q = bf16(q_feat+q_pos) [MQ_P][256]
__global__ __launch_bounds__(256) void prep_inputs(
    const float* __restrict__ src, const float* __restrict__ qf,
    const float* __restrict__ qp, __hip_bfloat16* __restrict__ src_bf,
    __hip_bfloat16* __restrict__ q_bf) {
  long idx = (long)blockIdx.x * 256 + threadIdx.x;
  union { __hip_bfloat16 h[8]; uint4 u; } o;
  if (idx < (long)MV_P * 32) {
    int row = idx >> 5, c8 = (idx & 31) * 8;
    if (row < B_ * S_) {
      const float4 a = *reinterpret_cast<const float4*>(src + (long)row * 256 + c8);
      const float4 b = *reinterpret_cast<const float4*>(src + (long)row * 256 + c8 + 4);
      o.h[0] = __float2bfloat16(a.x); o.h[1] = __float2bfloat16(a.y);
      o.h[2] = __float2bfloat16(a.z); o.h[3] = __float2bfloat16(a.w);
      o.h[4] = __float2bfloat16(b.x); o.h[5] = __float2bfloat16(b.y);
      o.h[6] = __float2bfloat16(b.z); o.h[7] = __float2bfloat16(b.w);
    } else o.u = make_uint4(0, 0, 0, 0);
    *reinterpret_cast<uint4*>(src_bf + (long)row * 256 + c8) = o.u;
  } else {
    idx -= (long)MV_P * 32;
    int row = idx >> 5, c8 = (idx & 31) * 8;
    if (row < B_ * NQ_) {
      const float4 a0 = *reinterpret_cast<const float4*>(qf + (long)row * 256 + c8);
      const float4 a1 = *reinterpret_cast<const float4*>(qf + (long)row * 256 + c8 + 4);
      const float4 b0 = *reinterpret_cast<const float4*>(qp + (long)row * 256 + c8);
      const float4 b1 = *reinterpret_cast<const float4*>(qp + (long)row * 256 + c8 + 4);
      o.h[0] = __float2bfloat16(a0.x + b0.x); o.h[1] = __float2bfloat16(a0.y + b0.y);
      o.h[2] = __float2bfloat16(a0.z + b0.z); o.h[3] = __float2bfloat16(a0.w + b0.w);
      o.h[4] = __float2bfloat16(a1.x + b1.x); o.h[5] = __float2bfloat16(a1.y + b1.y);
      o.h[6] = __float2bfloat16(a1.z + b1.z); o.h[7] = __float2bfloat16(a1.w + b1.w);
    } else o.u = make_uint4(0, 0, 0, 0);
    *reinterpret_cast<uint4*>(q_bf + (long)row * 256 + c8) = o.u;
  }
}

// ------------------------------------------------------------- MFMA GEMM
// C[M,N] = A[M,K] @ Bt[N,K]^T + bias. Tile 64x128, BK=64, 256 thr (2x2 waves).
// XOR-swizzled LDS (pre-swizzled global source + swizzled ds_read).
// bias: col<bsplit -> bias[col], else bias2[col-bsplit].
// MODE 0: f32 out. MODE 2: bf16 out + ReLU. MODE 3: bf16 scatter to
// value layout [B][NH][S][DH] (guard row<Mreal). MODE 4: bf16 out.
template <int MODE>
__global__ __launch_bounds__(256) void gemm_bf16(
    const __hip_bfloat16* __restrict__ A, const __hip_bfloat16* __restrict__ Bt,
    const float* __restrict__ bias, const float* __restrict__ bias2, int bsplit,
    void* __restrict__ Cp, int M, int N, int K, int Mreal) {
  __shared__ short smA[64 * 64];    // 8KB
  __shared__ short smB[128 * 64];   // 16KB
  const int tid = threadIdx.x;
  const int lane = tid & 63;
  const int w = tid >> 6;
  const int wr = w >> 1, wc = w & 1;
  const long bm = (long)blockIdx.x * 64;
  const long bn = (long)blockIdx.y * 128;

  f32x4 acc[2][4];
#pragma unroll
  for (int i = 0; i < 2; ++i)
#pragma unroll
    for (int j = 0; j < 4; ++j) acc[i][j] = (f32x4)(0.f);

  const int srow = tid >> 3;                 // 0..31
  const int su = (tid & 7) ^ (srow & 7);     // pre-swizzled k-unit
  const __hip_bfloat16* Ag = A + (bm + srow) * (long)K + su * 8;
  const __hip_bfloat16* Bg = Bt + (bn + srow) * (long)K + su * 8;
  char* lA = (char*)smA + tid * 16;
  char* lB = (char*)smB + tid * 16;

  for (int k0 = 0; k0 < K; k0 += 64) {
    gload16(Ag,           lA);
    gload16(Ag + 32L * K, lA + 4096);
    gload16(Bg,           lB);
    gload16(Bg + 32L * K, lB + 4096);
    gload16(Bg + 64L * K, lB + 8192);
    gload16(Bg + 96L * K, lB + 12288);
    Ag += 64; Bg += 64;
    __syncthreads();
#pragma unroll
    for (int ks = 0; ks < 2; ++ks) {
      const int u = ks * 4 + (lane >> 4);
      short8 af[2], bf[4];
#pragma unroll
      for (int mi = 0; mi < 2; ++mi) {
        const int r = wr * 32 + (lane & 15) + mi * 16;
        af[mi] = *reinterpret_cast<const short8*>(
            (char*)smA + r * 128 + ((u ^ (r & 7)) * 16));
      }
#pragma unroll
      for (int ni = 0; ni < 4; ++ni) {
        const int r = wc * 64 + (lane & 15) + ni * 16;
        bf[ni] = *reinterpret_cast<const short8*>(
            (char*)smB + r * 128 + ((u ^ (r & 7)) * 16));
      }
#pragma unroll
      for (int mi = 0; mi < 2; ++mi)
#pragma unroll
        for (int ni = 0; ni < 4; ++ni)
          acc[mi][ni] = __builtin_amdgcn_mfma_f32_16x16x32_bf16(af[mi], bf[ni], acc[mi][ni], 0, 0, 0);
    }
    __syncthreads();
  }

  const int crow0 = wr * 32 + ((lane >> 4) << 2);
  const int ccol0 = wc * 64 + (lane & 15);
#pragma unroll
  for (int mi = 0; mi < 2; ++mi) {
#pragma unroll
    for (int ni = 0; ni < 4; ++ni) {
      const int col = bn + ccol0 + ni * 16;
      const float bs = (col < bsplit) ? bias[col] : bias2[col - bsplit];
#pragma unroll
      for (int r = 0; r < 4; ++r) {
        const long row = bm + crow0 + mi * 16 + r;
        float v = acc[mi][ni][r] + bs;
        if (MODE == 0) {
          ((float*)Cp)[row * N + col] = v;
        } else if (MODE == 2) {
          ((__hip_bfloat16*)Cp)[row * N + col] = __float2bfloat16(fmaxf(v, 0.f));
        } else if (MODE == 4) {
          ((__hip_bfloat16*)Cp)[row * N + col] = __float2bfloat16(v);
        } else { // MODE 3
          if (row < Mreal) {
            const int b = (row >= S_) ? 1 : 0;
            const long s = row - (long)b * S_;
            const int h = col >> 5, dh = col & 31;
            ((__hip_bfloat16*)Cp)[(((long)(b * 8 + h)) * S_ + s) * 32 + dh] = __float2bfloat16(v);
          }
        }
      }
    }
  }
}

// ------------------------------------------------------------- ms_deform
// value bf16 [B][NH][S][32]; oa bf16 [bq][384]: cols 0..255 offsets (h,l,p,2),
// cols 256..383 logits (h,l*p). out bf16 [MQ_P][256] rows<20000.
// One wave per query: lane = dq(1b) | l(2b) | h(3b). Each lane: 16 channels,
// one level, 4 points. Cross-lane reduce over l via shfl_xor(2,4).
__global__ __launch_bounds__(256) void msdeform_kernel(
    const __hip_bfloat16* __restrict__ value, const __hip_bfloat16* __restrict__ oa,
    const float* __restrict__ q_ref, const float* __restrict__ vr,
    __hip_bfloat16* __restrict__ out) {
  const int t = blockIdx.x * 256 + threadIdx.x;
  const int dq = t & 1;
  const int l = (t >> 1) & 3;
  const int h = (t >> 3) & 7;
  const int bq = t >> 6;
  const int b = (bq >= NQ_) ? 1 : 0;

  const int W  = (l == 0) ? 160 : (l == 1) ? 80 : (l == 2) ? 40 : 20;
  const int H  = (l == 0) ? 92  : (l == 1) ? 46 : (l == 2) ? 23 : 12;
  const int S0 = (l == 0) ? 0 : (l == 1) ? 14720 : (l == 2) ? 18400 : 19320;

  // softmax normalizer over all 16 logits of head h
  const __hip_bfloat16* lgp = oa + (long)bq * 384 + 256 + h * 16;
  const uint4 g0 = *reinterpret_cast<const uint4*>(lgp);
  const uint4 g1 = *reinterpret_cast<const uint4*>(lgp + 8);
  float lv[16] = {bflo(g0.x), bfhi(g0.x), bflo(g0.y), bfhi(g0.y),
                  bflo(g0.z), bfhi(g0.z), bflo(g0.w), bfhi(g0.w),
                  bflo(g1.x), bfhi(g1.x), bflo(g1.y), bfhi(g1.y),
                  bflo(g1.z), bfhi(g1.z), bflo(g1.w), bfhi(g1.w)};
  float mx = lv[0];
#pragma unroll
  for (int j = 1; j < 16; ++j) mx = fmaxf(mx, lv[j]);
  float sum = 0.f;
#pragma unroll
  for (int j = 0; j < 16; ++j) sum += __expf(lv[j] - mx);
  const float inv = 1.f / sum;

  // this lane's 4 logits / 4 offset pairs (runtime l only in ADDRESS)
  const uint2 mu = *reinterpret_cast<const uint2*>(lgp + l * 4);
  const float w0 = __expf(bflo(mu.x) - mx) * inv;
  const float w1 = __expf(bfhi(mu.x) - mx) * inv;
  const float w2 = __expf(bflo(mu.y) - mx) * inv;
  const float w3 = __expf(bfhi(mu.y) - mx) * inv;
  const uint4 ou = *reinterpret_cast<const uint4*>(oa + (long)bq * 384 + h * 32 + l * 8);

  const float rx = q_ref[(long)bq * 2 + 0];
  const float ry = q_ref[(long)bq * 2 + 1];
  const float vrx = vr[(b * 4 + l) * 2 + 0];
  const float vry = vr[(b * 4 + l) * 2 + 1];
  const float refxW = rx * vrx * W - 0.5f;
  const float refyH = ry * vry * H - 0.5f;
  const __hip_bfloat16* vb = value + ((long)(b * 8 + h) * S_ + S0) * 32 + dq * 16;

  float acc[16] = {};
#define SAMPLE(OX, OY, AW)                                                     \
  {                                                                            \
    const float x = refxW + (OX);                                              \
    const float y = refyH + (OY);                                              \
    const float x0f = floorf(x), y0f = floorf(y);                              \
    const float lx = x - x0f, ly = y - y0f;                                    \
    const int x0 = (int)x0f, y0 = (int)y0f;                                    \
    const int x1 = x0 + 1, y1 = y0 + 1;                                        \
    const float wx0 = ((unsigned)x0 < (unsigned)W) ? (1.f - lx) : 0.f;         \
    const float wx1 = ((unsigned)x1 < (unsigned)W) ? lx : 0.f;                 \
    const float wy0 = ((unsigned)y0 < (unsigned)H) ? (1.f - ly) : 0.f;         \
    const float wy1 = ((unsigned)y1 < (unsigned)H) ? ly : 0.f;                 \
    const int x0c = min(max(x0, 0), W - 1);                                    \
    const int x1c = min(max(x1, 0), W - 1);                                    \
    const int y0c = min(max(y0, 0), H - 1);                                    \
    const int y1c = min(max(y1, 0), H - 1);                                    \
    const float w00 = (AW) * wx0 * wy0, w10 = (AW) * wx1 * wy0;                \
    const float w01 = (AW) * wx0 * wy1, w11 = (AW) * wx1 * wy1;                \
    const __hip_bfloat16* p00 = vb + (long)(y0c * W + x0c) * 32;               \
    const __hip_bfloat16* p10 = vb + (long)(y0c * W + x1c) * 32;               \
    const __hip_bfloat16* p01 = vb + (long)(y1c * W + x0c) * 32;               \
    const __hip_bfloat16* p11 = vb + (long)(y1c * W + x1c) * 32;               \
    const uint4 a0 = *reinterpret_cast<const uint4*>(p00);                     \
    const uint4 a1 = *reinterpret_cast<const uint4*>(p00 + 8);                 \
    const uint4 b0 = *reinterpret_cast<const uint4*>(p10);                     \
    const uint4 b1 = *reinterpret_cast<const uint4*>(p10 + 8);                 \
    const uint4 c0 = *reinterpret_cast<const uint4*>(p01);                     \
    const uint4 c1 = *reinterpret_cast<const uint4*>(p01 + 8);                 \
    const uint4 d0 = *reinterpret_cast<const uint4*>(p11);                     \
    const uint4 d1 = *reinterpret_cast<const uint4*>(p11 + 8);                 \
    acc[0] += w00 * bflo(a0.x) + w10 * bflo(b0.x) + w01 * bflo(c0.x) + w11 * bflo(d0.x); \
    acc[1] += w00 * bfhi(a0.x) + w10 * bfhi(b0.x) + w01 * bfhi(c0.x) + w11 * bfhi(d0.x); \
    acc[2] += w00 * bflo(a0.y) + w10 * bflo(b0.y) + w01 * bflo(c0.y) + w11 * bflo(d0.y); \
    acc[3] += w00 * bfhi(a0.y) + w10 * bfhi(b0.y) + w01 * bfhi(c0.y) + w11 * bfhi(d0.y); \
    acc[4] += w00 * bflo(a0.z) + w10 * bflo(b0.z) + w01 * bflo(c0.z) + w11 * bflo(d0.z); \
    acc[5] += w00 * bfhi(a0.z) + w10 * bfhi(b0.z) + w01 * bfhi(c0.z) + w11 * bfhi(d0.z); \
    acc[6] += w00 * bflo(a0.w) + w10 * bflo(b0.w) + w01 * bflo(c0.w) + w11 * bflo(d0.w); \
    acc[7] += w00 * bfhi(a0.w) + w10 * bfhi(b0.w) + w01 * bfhi(c0.w) + w11 * bfhi(d0.w); \
    acc[8]  += w00 * bflo(a1.x) + w10 * bflo(b1.x) + w01 * bflo(c1.x) + w11 * bflo(d1.x); \
    acc[9]  += w00 * bfhi(a1.x) + w10 * bfhi(b1.x) + w01 * bfhi(c1.x) + w11 * bfhi(d1.x); \
    acc[10] += w00 * bflo(a1.y) + w10 * bflo(b1.y) + w01 * bflo(c1.y) + w11 * bflo(d1.y); \
    acc[11] += w00 * bfhi(a1.y) + w10 * bfhi(b1.y) + w01 * bfhi(c1.y) + w11 * bfhi(d1.y); \
    acc[12] += w00 * bflo(a1.z) + w10 * bflo(b1.z) + w01 * bflo(c1.z) + w11 * bflo(d1.z); \
    acc[13] += w00 * bfhi(a1.z) + w10 * bfhi(b1.z) + w01 * bfhi(c1.z) + w11 * bfhi(d1.z); \
    acc[14] += w00 * bflo(a1.w) + w10 * bflo(b1.w) + w01 * bflo(c1.w) + w11 * bflo(d1.w); \
    acc[15] += w00 * bfhi(a1.w) + w10 * bfhi(b1.w) + w01 * bfhi(c1.w) + w11 * bfhi(d1.w); \
  }
  SAMPLE(bflo(ou.x), bfhi(ou.x), w0)
  SAMPLE(bflo(ou.y), bfhi(ou.y), w1)
  SAMPLE(bflo(ou.z), bfhi(ou.z), w2)
  SAMPLE(bflo(ou.w), bfhi(ou.w), w3)
#undef SAMPLE

#pragma unroll
  for (int j = 0; j < 16; ++j) acc[j] += __shfl_xor(acc[j], 2, 64);
#pragma unroll
  for (int j = 0; j < 16; ++j) acc[j] += __shfl_xor(acc[j], 4, 64);

  if (l == 0) {
    union { __hip_bfloat16 hh[8]; uint4 u; } o0, o1;
#pragma unroll
    for (int j = 0; j < 8; ++j) {
      o0.hh[j] = __float2bfloat16(acc[j]);
      o1.hh[j] = __float2bfloat16(acc[j + 8]);
    }
    __hip_bfloat16* op = out + (long)bq * 256 + h * 32 + dq * 16;
    *reinterpret_cast<uint4*>(op) = o0.u;
    *reinterpret_cast<uint4*>(op + 8) = o1.u;
  }
}

// ------------------------------------------------------------- residual+LN
__global__ __launch_bounds__(256) void add_ln_kernel(
    const float* __restrict__ res, const float* __restrict__ xin,
    const float* __restrict__ gamma, const float* __restrict__ beta,
    float* __restrict__ out, __hip_bfloat16* __restrict__ out_bf, int nrows) {
  int row = blockIdx.x * 4 + (threadIdx.x >> 6);
  int lane = threadIdx.x & 63;
  if (row >= nrows) return;
  const float4 r4 = *reinterpret_cast<const float4*>(res + (long)row * 256 + lane * 4);
  const float4 x4 = *reinterpret_cast<const float4*>(xin + (long)row * 256 + lane * 4);
  float tv[4] = {r4.x + x4.x, r4.y + x4.y, r4.z + x4.z, r4.w + x4.w};
  float s = tv[0] + tv[1] + tv[2] + tv[3];
#pragma unroll
  for (int o = 32; o > 0; o >>= 1) s += __shfl_xor(s, o, 64);
  float mean = s * (1.f / 256.f);
  float vs = 0.f;
#pragma unroll
  for (int j = 0; j < 4; ++j) { float dd = tv[j] - mean; vs += dd * dd; }
#pragma unroll
  for (int o = 32; o > 0; o >>= 1) vs += __shfl_xor(vs, o, 64);
  float inv = rsqrtf(vs * (1.f / 256.f) + 1e-5f);
  const float4 g = *reinterpret_cast<const float4*>(gamma + lane * 4);
  const float4 be = *reinterpret_cast<const float4*>(beta + lane * 4);
  float4 o4;
  o4.x = (tv[0] - mean) * inv * g.x + be.x;
  o4.y = (tv[1] - mean) * inv * g.y + be.y;
  o4.z = (tv[2] - mean) * inv * g.z + be.z;
  o4.w = (tv[3] - mean) * inv * g.w + be.w;
  *reinterpret_cast<float4*>(out + (long)row * 256 + lane * 4) = o4;
  if (out_bf) {
    union { __hip_bfloat16 h[4]; uint2 u; } p;
    p.h[0] = __float2bfloat16(o4.x); p.h[1] = __float2bfloat16(o4.y);
    p.h[2] = __float2bfloat16(o4.z); p.h[3] = __float2bfloat16(o4.w);
    *reinterpret_cast<uint2*>(out_bf + (long)row * 256 + lane * 4) = p.u;
  }
}

// ------------------------------------------------------------- launch
extern "C" void kernel_launch(void* const* d_in, const int* in_sizes, int n_in,
                              void* d_out, int out_size, void* d_ws, size_t ws_size,
                              hipStream_t stream) {
  const float* src    = (const float*)d_in[0];
  const float* q_feat = (const float*)d_in[1];
  const float* q_pos  = (const float*)d_in[2];
  const float* q_ref  = (const float*)d_in[3];
  const float* vr     = (const float*)d_in[4];
  const float* Wv     = (const float*)d_in[5];
  const float* bv     = (const float*)d_in[6];
  const float* Woff   = (const float*)d_in[7];
  const float* boff   = (const float*)d_in[8];
  const float* Wa     = (const float*)d_in[9];
  const float* ba     = (const float*)d_in[10];
  const float* Wo     = (const float*)d_in[11];
  const float* bo     = (const float*)d_in[12];
  const float* g1     = (const float*)d_in[13];
  const float* be1    = (const float*)d_in[14];
  const float* W1     = (const float*)d_in[15];
  const float* bf1    = (const float*)d_in[16];
  const float* W2     = (const float*)d_in[17];
  const float* bf2    = (const float*)d_in[18];
  const float* g2     = (const float*)d_in[19];
  const float* be2    = (const float*)d_in[20];

  char* ws = (char*)d_ws;
  __hip_bfloat16* src_bf = (__hip_bfloat16*)(ws + 0);          // 20,054,016
  float*          a_f    = (float*)(ws + 0);                   // reuse (20,578,304)
  __hip_bfloat16* q_bf   = (__hip_bfloat16*)(ws + 20578304);   // 10,289,152
  __hip_bfloat16* val_bf = (__hip_bfloat16*)(ws + 30867456);   // 20,029,440
  __hip_bfloat16* oa_bf  = (__hip_bfloat16*)(ws + 50896896);   // 15,433,728
  __hip_bfloat16* h1_bf  = (__hip_bfloat16*)(ws + 20578304);   // reuse q/val/oa (41,156,608)
  __hip_bfloat16* ms_bf  = (__hip_bfloat16*)(ws + 81764352);   // 10,289,152
  float*          f2_f   = (float*)(ws + 71475200);            // 20,578,304 (dead region)
  float*          x_f    = (float*)(ws + 92053504);            // 20,578,304
  __hip_bfloat16* x_bf   = (__hip_bfloat16*)(ws + 112631808);  // 10,289,152
  __hip_bfloat16* wts    = (__hip_bfloat16*)(ws + 122920960);  // 1,507,328
  float* outp = (float*)d_out;

  const int Mq = B_ * NQ_;   // 20000
  const int Mv = B_ * S_;    // 39120
  const int BIG = 1 << 30;

  // weights -> bf16 transposed, packed
  conv_weights<<<2944, 256, 0, stream>>>(Wv, Woff, Wa, Wo, W1, W2, wts);
  // src -> bf16 padded; q = bf16(q_feat+q_pos) padded
  prep_inputs<<<(MV_P * 32 + MQ_P * 32) / 256, 256, 0, stream>>>(src, q_feat, q_pos, src_bf, q_bf);
  // value = src @ Wv + bv -> bf16 scatter [B][NH][S][DH]
  gemm_bf16<3><<<dim3(MV_P / 64, 2), 256, 0, stream>>>(src_bf, wts + 0, bv, bv, BIG, val_bf, MV_P, 256, 256, Mv);
  // [off | attn-logits] = q @ [Woff|Wa] + [boff|ba]  (bf16, N=384)
  gemm_bf16<4><<<dim3(MQ_P / 64, 3), 256, 0, stream>>>(q_bf, wts + 65536, boff, ba, 256, oa_bf, MQ_P, 384, 256, MQ_P);
  // deformable sampling (softmax fused) -> ms bf16
  msdeform_kernel<<<(Mq * 64) / 256, 256, 0, stream>>>(val_bf, oa_bf, q_ref, vr, ms_bf);
  // a = ms @ Wo + bo  (f32)
  gemm_bf16<0><<<dim3(MQ_P / 64, 2), 256, 0, stream>>>(ms_bf, wts + 163840, bo, bo, BIG, a_f, MQ_P, 256, 256, MQ_P);
  // x = LN(q_feat + a), plus bf16 copy
  add_ln_kernel<<<(Mq + 3) / 4, 256, 0, stream>>>(q_feat, a_f, g1, be1, x_f, x_bf, Mq);
  // h1 = relu(x @ W1 + bf1)  (bf16)
  gemm_bf16<2><<<dim3(MQ_P / 64, 8), 256, 0, stream>>>(x_bf, wts + 229376, bf1, bf1, BIG, h1_bf, MQ_P, 1024, 256, MQ_P);
  // f2 = h1 @ W2 + bf2  (f32)
  gemm_bf16<0><<<dim3(MQ_P / 64, 2), 256, 0, stream>>>(h1_bf, wts + 491520, bf2, bf2, BIG, f2_f, MQ_P, 256, 1024, MQ_P);
  // out = LN(x + f2)
  add_ln_kernel<<<(Mq + 3) / 4, 256, 0, stream>>>(x_f, f2_f, g2, be2, outp, nullptr, Mq);
}